// Round 10
// baseline (736.364 us; speedup 1.0000x reference)
//
#include <hip/hip_runtime.h>
#include <hip/hip_bf16.h>
#include <math.h>

#define BB 2
#define SS 2048
#define HH 4096
#define NH 32
#define NKV 8
#define HD 128
#define KVD (NKV*HD)    // 1024
#define WIN 512         // mask: j <= i && i-j <= 512
#define MROWS (BB*SS)   // 4096

#define DT_BF16 1
#define DT_F32  2

typedef __hip_bfloat16 bf16;
typedef __attribute__((ext_vector_type(8))) short short8;
typedef __attribute__((ext_vector_type(4))) float f32x4;

__device__ __forceinline__ float ldf(const bf16* p){ return __bfloat162float(*p); }
__device__ __forceinline__ float ldf(const float* p){ return *p; }
__device__ __forceinline__ void stf(bf16* p, float v){ *p = __float2bfloat16(v); }
__device__ __forceinline__ void stf(float* p, float v){ *p = v; }

// ---------- dtype detector (prior-session-proven) ----------
__global__ void detect_kernel(const void* __restrict__ w, int* __restrict__ flag)
{
  __shared__ int big;
  if (threadIdx.x == 0) big = 0;
  __syncthreads();
  const unsigned short* u = (const unsigned short*)w;
  for (int i = threadIdx.x; i < 2048; i += 256) {
    int ex = (u[i] >> 7) & 0xFF;
    if (ex >= 160) big = 1;
  }
  __syncthreads();
  if (threadIdx.x == 0) *flag = big ? DT_F32 : DT_BF16;
}

// ---------- X fp32 -> bf16 (no-op in bf16 mode; Y = d_out scratch) ----------
__global__ __launch_bounds__(256)
void cvt_x(const int* __restrict__ flag, const float* __restrict__ X,
           bf16* __restrict__ Y)
{
  if (*flag != DT_F32) return;
  const size_t idx = (size_t)blockIdx.x*256 + threadIdx.x;   // 8 floats/thread
  const f32x4 a = *(const f32x4*)(X + idx*8);
  const f32x4 b = *(const f32x4*)(X + idx*8 + 4);
  union { short8 s; bf16 h[8]; } u;
  #pragma unroll
  for (int j = 0; j < 4; j++) {
    u.h[j]     = __float2bfloat16(a[j]);
    u.h[j + 4] = __float2bfloat16(b[j]);
  }
  *(short8*)(Y + idx*8) = u.s;
}

// ------------- W [Kd,Nd] -> WT [Nd,Kd] bf16; dtype branched inside -------------
// Z=2 grid: blockIdx.z selects (W0->D0) or (W1->D1) for fused Wk/Wv transpose.
__global__ __launch_bounds__(256)
void transpose_cvt(const int* __restrict__ flag,
                   const void* W0, const void* W1,
                   bf16* D0, bf16* D1, int Kd, int Nd)
{
  const bool isf32 = (*flag == DT_F32);
  const void* W = blockIdx.z ? W1 : W0;
  bf16*     WT  = blockIdx.z ? D1 : D0;
  __shared__ float tile[32][33];
  const int n0 = blockIdx.x*32, k0 = blockIdx.y*32;
  const int tx = threadIdx.x & 31, ty = threadIdx.x >> 5;   // ty 0..7
  #pragma unroll
  for (int j = 0; j < 4; j++) {
    const size_t off = (size_t)(k0 + ty + j*8)*Nd + n0 + tx;
    tile[ty + j*8][tx] = isf32 ? ((const float*)W)[off]
                               : __bfloat162float(((const bf16*)W)[off]);
  }
  __syncthreads();
  #pragma unroll
  for (int j = 0; j < 4; j++)
    WT[(size_t)(n0 + ty + j*8)*Kd + k0 + tx] = __float2bfloat16(tile[tx][ty + j*8]);
}

// ======================= 256x256 MFMA GEMM (round-8 phase structure) =======================
// C[M,N] = A[M,K] @ B^T. BK=64, 512 thr (8 waves, 2M x 4N), LDS 128 KiB 2-dbuf.
// Per K-tile: {12 reads || stage -> lgkmcnt(0) -> setprio/MFMA -> barrier} x2,
// then {stage || MFMA -> barrier} x2 with counted vmcnt at the boundary.
#define MFMA16(a,b,c) __builtin_amdgcn_mfma_f32_16x16x32_bf16(a,b,c,0,0,0)

template<int OUTF>   // OUTF=1: C dtype follows flag (O-proj); OUTF=0: bf16 out
__global__ __launch_bounds__(512)
void gemm256(const int* __restrict__ flag,
             const bf16* __restrict__ Abf, const bf16* __restrict__ Axb,
             const bf16* __restrict__ Bm, void* __restrict__ C,
             int M, int N, int K)
{
  const bool isf32 = (*flag == DT_F32);
  const bf16* A = isf32 ? Axb : Abf;
  __shared__ __align__(16) bf16 lds[65536];   // 128 KiB; 16B chunks: A 0..4095, B 4096..8191
  const int tid = threadIdx.x;
  const int w = tid >> 6, lane = tid & 63;
  const int wm = w >> 2, wn = w & 3;
  const int fr = lane & 15, fq = lane >> 4;

  // XCD-aware bijective swizzle (nwg = 256, divisible by 8)
  const int gx = gridDim.x;
  int wg = blockIdx.y*gx + blockIdx.x;
  const int cpx = (gx*gridDim.y) >> 3;
  wg = (wg & 7)*cpx + (wg >> 3);
  const int tM = (wg / gx)*256, tN = (wg % gx)*256;

  const int NT = K >> 6;   // K-tiles of 64

  auto stage = [&](int tt, int s){
    const int dbuf = tt & 1;
    const int hf = s & 1;
    const bf16* src = (s < 2) ? A : Bm;
    const int brow = ((s < 2) ? tM : tN) + hf*128;
    const int cbase = ((s < 2) ? 0 : 4096) + (dbuf*2 + hf)*1024;
    #pragma unroll
    for (int g = 0; g < 2; g++) {
      const int Ch = g*512 + tid;          // chunk 0..1023 within half-tile
      const int r = Ch >> 3, c = Ch & 7;
      const int cs = c ^ (r & 7);
      const bf16* gp = src + (size_t)(brow + r)*K + tt*64 + cs*8;
      char* lp = (char*)lds + (size_t)(cbase + g*512 + w*64)*16;   // + lane*16 by HW
      __builtin_amdgcn_global_load_lds((const __attribute__((address_space(1))) void*)gp,
                                       (__attribute__((address_space(3))) void*)lp, 16, 0, 0);
    }
  };
  auto rdA = [&](int dbuf, int m, int kk) -> short8 {
    const int r = m*16 + fr;                       // row within half (half = wm)
    const int chunk = (dbuf*2 + wm)*1024 + r*8 + ((kk*4 + fq) ^ (r & 7));
    return *(const short8*)((char*)lds + (size_t)chunk*16);
  };
  auto rdB = [&](int dbuf, int n, int kk) -> short8 {
    const int rg = wn*64 + n*16 + fr;              // 0..255
    const int hf = rg >> 7, rr = rg & 127;
    const int chunk = 4096 + (dbuf*2 + hf)*1024 + rr*8 + ((kk*4 + fq) ^ (rr & 7));
    return *(const short8*)((char*)lds + (size_t)chunk*16);
  };

  f32x4 acc[8][4] = {};

  #pragma unroll
  for (int s = 0; s < 4; s++) stage(0, s);
  stage(1, 0); stage(1, 1);
  asm volatile("s_waitcnt vmcnt(4)" ::: "memory");
  __builtin_amdgcn_s_barrier();

  short8 a0[4][2], a1[4][2], b0[2][2], b1[2][2];
  for (int kt = 0; kt < NT; kt++) {
    const int db = kt & 1;
    // -- phase 0: read a0+b0; stage (kt+1).B.h0; MFMA m0-3 x n0-1
    #pragma unroll
    for (int m = 0; m < 4; m++){ a0[m][0]=rdA(db,m,0); a0[m][1]=rdA(db,m,1); }
    #pragma unroll
    for (int n = 0; n < 2; n++){ b0[n][0]=rdB(db,n,0); b0[n][1]=rdB(db,n,1); }
    if (kt+1 < NT) stage(kt+1, 2);
    asm volatile("s_waitcnt lgkmcnt(0)" ::: "memory");
    __builtin_amdgcn_sched_barrier(0);
    __builtin_amdgcn_s_setprio(1);
    #pragma unroll
    for (int m = 0; m < 4; m++)
      #pragma unroll
      for (int n = 0; n < 2; n++){
        acc[m][n] = MFMA16(a0[m][0], b0[n][0], acc[m][n]);
        acc[m][n] = MFMA16(a0[m][1], b0[n][1], acc[m][n]);
      }
    __builtin_amdgcn_s_setprio(0);
    __builtin_amdgcn_s_barrier();
    // -- phase 1: read a1+b1; stage (kt+1).B.h1; MFMA m4-7 x n2-3
    #pragma unroll
    for (int m = 0; m < 4; m++){ a1[m][0]=rdA(db,m+4,0); a1[m][1]=rdA(db,m+4,1); }
    #pragma unroll
    for (int n = 0; n < 2; n++){ b1[n][0]=rdB(db,n+2,0); b1[n][1]=rdB(db,n+2,1); }
    if (kt+1 < NT) stage(kt+1, 3);
    asm volatile("s_waitcnt lgkmcnt(0)" ::: "memory");
    __builtin_amdgcn_sched_barrier(0);
    __builtin_amdgcn_s_setprio(1);
    #pragma unroll
    for (int m = 0; m < 4; m++)
      #pragma unroll
      for (int n = 0; n < 2; n++){
        acc[m+4][n+2] = MFMA16(a1[m][0], b1[n][0], acc[m+4][n+2]);
        acc[m+4][n+2] = MFMA16(a1[m][1], b1[n][1], acc[m+4][n+2]);
      }
    __builtin_amdgcn_s_setprio(0);
    __builtin_amdgcn_s_barrier();       // all dbuf(kt) LDS reads complete
    // -- phase 2: stage (kt+2).A.h0 (dbuf now dead); MFMA m0-3 x n2-3
    if (kt+2 < NT) stage(kt+2, 0);
    __builtin_amdgcn_s_setprio(1);
    #pragma unroll
    for (int m = 0; m < 4; m++)
      #pragma unroll
      for (int n = 0; n < 2; n++){
        acc[m][n+2] = MFMA16(a0[m][0], b1[n][0], acc[m][n+2]);
        acc[m][n+2] = MFMA16(a0[m][1], b1[n][1], acc[m][n+2]);
      }
    __builtin_amdgcn_s_setprio(0);
    __builtin_amdgcn_s_barrier();
    // -- phase 3: stage (kt+2).A.h1; MFMA m4-7 x n0-1
    if (kt+2 < NT) stage(kt+2, 1);
    __builtin_amdgcn_s_setprio(1);
    #pragma unroll
    for (int m = 0; m < 4; m++)
      #pragma unroll
      for (int n = 0; n < 2; n++){
        acc[m+4][n] = MFMA16(a1[m][0], b0[n][0], acc[m+4][n]);
        acc[m+4][n] = MFMA16(a1[m][1], b0[n][1], acc[m+4][n]);
      }
    __builtin_amdgcn_s_setprio(0);
    // -- K-tile boundary: counted wait (never 0 in steady state) + barrier
    if (kt+2 < NT) { asm volatile("s_waitcnt vmcnt(4)" ::: "memory"); }
    else           { asm volatile("s_waitcnt vmcnt(0)" ::: "memory"); }
    __builtin_amdgcn_s_barrier();
  }

  // ---- epilogue: C/D layout col=lane&15, row=(lane>>4)*4+reg ----
  #pragma unroll
  for (int m = 0; m < 8; m++)
    #pragma unroll
    for (int n = 0; n < 4; n++)
      #pragma unroll
      for (int r = 0; r < 4; r++) {
        const size_t off = (size_t)(tM + wm*128 + m*16 + fq*4 + r)*N
                         + (tN + wn*64 + n*16 + fr);
        if (OUTF && isf32) ((float*)C)[off] = acc[m][n][r];
        else               stf((bf16*)C + off, acc[m][n][r]);
      }
}

// ---------------- Fused K+V projection (m97 128x128 structure) ----------------
// blockIdx.z: 0 -> K = X@WTk^T (row-major); 1 -> V -> VT[b][kh][d][s].
__global__ __launch_bounds__(256)
void gemm_kv(const int* __restrict__ flag,
             const bf16* __restrict__ Abf, const bf16* __restrict__ Axb,
             const bf16* __restrict__ WTk, const bf16* __restrict__ WTv,
             bf16* __restrict__ Kout, bf16* __restrict__ VTout, int M, int N, int K)
{
  const bf16* A = (*flag == DT_F32) ? Axb : Abf;
  const bool vpath = blockIdx.z != 0;
  const bf16* Bm = vpath ? WTv : WTk;
  __shared__ __align__(16) bf16 As[128*32];
  __shared__ __align__(16) bf16 Bs[128*32];
  const int tid  = threadIdx.x;
  const int w    = tid >> 6;
  const int lane = tid & 63;
  const int wr = w >> 1, wc = w & 1;
  const int tM = blockIdx.y*128, tN = blockIdx.x*128;
  const int srow = tid >> 2;          // 0..63
  const int scol = (tid & 3) * 8;     // 0,8,16,24
  const int fr = lane & 15;
  const int kq = (lane >> 4) * 8;

  f32x4 acc[4][4] = {};

  for (int k0 = 0; k0 < K; k0 += 32) {
    __syncthreads();
    #pragma unroll
    for (int q = 0; q < 2; q++) {
      const int row = q*64 + srow;
      const bf16* ga = A  + (size_t)(tM + row)*K + k0 + scol;
      const bf16* gb = Bm + (size_t)(tN + row)*K + k0 + scol;
      char* la = (char*)As + q*4096 + w*1024;   // wave-uniform base; HW adds lane*16
      char* lb = (char*)Bs + q*4096 + w*1024;
      __builtin_amdgcn_global_load_lds((const __attribute__((address_space(1))) void*)ga,
                                       (__attribute__((address_space(3))) void*)la, 16, 0, 0);
      __builtin_amdgcn_global_load_lds((const __attribute__((address_space(1))) void*)gb,
                                       (__attribute__((address_space(3))) void*)lb, 16, 0, 0);
    }
    __syncthreads();

    short8 af[4], bfr[4];
    #pragma unroll
    for (int m = 0; m < 4; m++) af[m]  = *(const short8*)&As[(wr*64 + m*16 + fr)*32 + kq];
    #pragma unroll
    for (int n = 0; n < 4; n++) bfr[n] = *(const short8*)&Bs[(wc*64 + n*16 + fr)*32 + kq];
    #pragma unroll
    for (int m = 0; m < 4; m++)
      #pragma unroll
      for (int n = 0; n < 4; n++)
        acc[m][n] = MFMA16(af[m], bfr[n], acc[m][n]);
  }

  const int fq = lane >> 4;
  #pragma unroll
  for (int m = 0; m < 4; m++)
    #pragma unroll
    for (int n = 0; n < 4; n++)
      #pragma unroll
      for (int r = 0; r < 4; r++) {
        const int gm = tM + wr*64 + m*16 + fq*4 + r;
        const int gn = tN + wc*64 + n*16 + fr;
        if (vpath) {
          // VT[b][kh][d][s]: b=gm>>11, s=gm&2047, kh=gn>>7, d=gn&127
          size_t idx = ((size_t)((gm >> 11)*NKV + (gn >> 7)))*((size_t)HD*SS)
                     + (size_t)(gn & 127)*SS + (gm & 2047);
          stf(VTout + idx, acc[m][n][r]);
        } else {
          stf(Kout + (size_t)gm*N + gn, acc[m][n][r]);
        }
      }
}

// ---------------- RoPE (in place, Q and K in one dispatch) ----------------
__global__ void rope_kernel(bf16* __restrict__ Qb, bf16* __restrict__ Kb)
{
  int idx = blockIdx.x*blockDim.x + threadIdx.x;
  int total = MROWS * (NH + NKV) * 64;
  if (idx >= total) return;
  int f   = idx & 63;
  int rem = idx >> 6;
  int h   = rem % (NH + NKV);
  int row = rem / (NH + NKV);
  int s   = row & (SS - 1);
  float ang = (float)s * exp2f((float)f * -0.20762050593046014f);
  float sv, cv;
  __sincosf(ang, &sv, &cv);
  bf16* X; int nh2; int hh;
  if (h < NH) { X = Qb; hh = h; nh2 = NH; }
  else        { X = Kb; hh = h - NH; nh2 = NKV; }
  size_t base = (size_t)row*nh2*HD + (size_t)hh*HD;
  float x1 = ldf(X + base + f), x2 = ldf(X + base + 64 + f);
  stf(X + base + f,      x1*cv - x2*sv);
  stf(X + base + 64 + f, x2*cv + x1*sv);
}

// ---------------- Flash-tile MFMA attention (staged K/V + T14 async split) ----------------
// Block = (b, h, 64-row q-tile); 4 waves x 16 q-rows; KV tiles of 64.
// LDS 40 KB -> 3 blocks/CU (launch_bounds(256,3), VGPR cap ~168).
__global__ __launch_bounds__(256, 3)
void attn_mfma(const bf16* __restrict__ Q, const bf16* __restrict__ K,
               const bf16* __restrict__ VT, bf16* __restrict__ Aout)
{
  int flat = (blockIdx.z*NH + blockIdx.y)*(SS/64) + blockIdx.x;
  flat = (flat & 7)*(BB*NH*(SS/64)/8) + (flat >> 3);   // bijective (2048 % 8 == 0)
  const int i0 = (flat & 31) * 64;
  const int h  = (flat >> 5) & 31;
  const int b  = flat >> 10;
  const int kh = h >> 2;
  const int tid = threadIdx.x;
  const int w = tid >> 6, lane = tid & 63;
  const int fr = lane & 15, fq = lane >> 4;

  __shared__ __align__(16) bf16 Ks[64*128];
  __shared__ __align__(16) bf16 Vs[128*64];
  __shared__ __align__(16) bf16 Ps[4][16*64];

  // ---- Q fragments direct from global (once per block) ----
  const int qrow = w*16 + fr;
  const bf16* gq = Q + (size_t)(b*SS + i0 + qrow)*HH + h*HD + fq*8;
  short8 qf[4];
  #pragma unroll
  for (int kk = 0; kk < 4; kk++) qf[kk] = *(const short8*)(gq + kk*32);

  // T14 staging registers (4 K + 4 V short8 per thread)
  short8 kreg[4], vreg[4];
  auto loadKV = [&](int j0){
    const bf16* gk = K + (size_t)(b*SS + j0)*KVD + kh*HD;
    #pragma unroll
    for (int it = 0; it < 4; it++) {
      int slot = tid + it*256;
      int r = slot >> 4, cg = slot & 15;
      kreg[it] = *(const short8*)(gk + (size_t)r*KVD + cg*8);
    }
    const bf16* gv = VT + ((size_t)(b*NKV + kh)*HD)*SS + j0;
    #pragma unroll
    for (int it = 0; it < 4; it++) {
      int slot = tid + it*256;
      int d = slot >> 3, jg = slot & 7;
      vreg[it] = *(const short8*)(gv + (size_t)d*SS + jg*8);
    }
  };
  auto writeKV = [&](){
    #pragma unroll
    for (int it = 0; it < 4; it++) {
      int slot = tid + it*256;
      int r = slot >> 4, cg = slot & 15;
      *(short8*)((char*)Ks + r*256 + ((cg*16) ^ ((r & 7) << 4))) = kreg[it];
      int d = slot >> 3, jg = slot & 7;
      *(short8*)((char*)Vs + d*128 + ((jg*16) ^ ((d & 7) << 4))) = vreg[it];
    }
  };

  const float scale = 0.08838834764831845f;   // 1/sqrt(128)
  f32x4 o[8];
  #pragma unroll
  for (int nn = 0; nn < 8; nn++) o[nn] = (f32x4){0.f, 0.f, 0.f, 0.f};
  float m_run[4] = {-1e30f, -1e30f, -1e30f, -1e30f};
  float l_run[4] = {0.f, 0.f, 0.f, 0.f};

  const int j0_lo = (i0 >= WIN) ? (i0 - WIN) : 0;
  loadKV(j0_lo);

  for (int j0 = j0_lo; j0 <= i0; j0 += 64) {
    // ---- write staged regs -> LDS (prev tile's LDS reads done: end barrier) ----
    writeKV();
    __syncthreads();

    // ---- QK^T: S[q=fq*4+r][j=jf*16+fr] from Ks ----
    f32x4 sv[4];
    #pragma unroll
    for (int jf = 0; jf < 4; jf++) sv[jf] = (f32x4){0.f, 0.f, 0.f, 0.f};
    #pragma unroll
    for (int kk = 0; kk < 4; kk++) {
      #pragma unroll
      for (int jf = 0; jf < 4; jf++) {
        const int krow = jf*16 + fr;
        short8 kf = *(const short8*)((char*)Ks + krow*256 + ((kk*64 + fq*16) ^ ((krow & 7) << 4)));
        sv[jf] = MFMA16(qf[kk], kf, sv[jf]);
      }
    }

    // ---- T14: issue next tile's loads now; latency hides under softmax+PV ----
    if (j0 + 64 <= i0) loadKV(j0 + 64);

    // ---- scale + mask ----
    const bool needmask = !((j0 >= i0 - 448) && (j0 <= i0 - 64));
    #pragma unroll
    for (int jf = 0; jf < 4; jf++)
      #pragma unroll
      for (int r = 0; r < 4; r++) {
        float x = sv[jf][r] * scale;
        if (needmask) {
          int iq = i0 + w*16 + fq*4 + r;
          int jv = j0 + jf*16 + fr;
          if (jv > iq || iq - jv > WIN) x = -1e30f;
        }
        sv[jf][r] = x;
      }

    // ---- online softmax (rows q = fq*4+r; in-reg + 16-lane xor reduce) ----
    float fac[4];
    #pragma unroll
    for (int r = 0; r < 4; r++) {
      float t = fmaxf(fmaxf(sv[0][r], sv[1][r]), fmaxf(sv[2][r], sv[3][r]));
      t = fmaxf(t, __shfl_xor(t, 1));
      t = fmaxf(t, __shfl_xor(t, 2));
      t = fmaxf(t, __shfl_xor(t, 4));
      t = fmaxf(t, __shfl_xor(t, 8));
      float mn = fmaxf(m_run[r], t);
      fac[r] = __expf(m_run[r] - mn);
      m_run[r] = mn;
    }
    #pragma unroll
    for (int r = 0; r < 4; r++) {
      float sum = 0.f;
      #pragma unroll
      for (int jf = 0; jf < 4; jf++) {
        float p = __expf(sv[jf][r] - m_run[r]);
        sv[jf][r] = p;
        sum += p;
      }
      sum += __shfl_xor(sum, 1);
      sum += __shfl_xor(sum, 2);
      sum += __shfl_xor(sum, 4);
      sum += __shfl_xor(sum, 8);
      l_run[r] = l_run[r]*fac[r] + sum;
    }

    // ---- P -> per-wave LDS (swizzled), reach A-operand layout ----
    char* pbase = (char*)(&Ps[w][0]);
    #pragma unroll
    for (int jf = 0; jf < 4; jf++)
      #pragma unroll
      for (int r = 0; r < 4; r++) {
        int q = fq*4 + r, j = jf*16 + fr;
        *(bf16*)(pbase + q*128 + ((j*2) ^ ((q & 7) << 4))) = __float2bfloat16(sv[jf][r]);
      }

    // ---- rescale O, then PV from Vs ----
    #pragma unroll
    for (int nn = 0; nn < 8; nn++)
      #pragma unroll
      for (int r = 0; r < 4; r++) o[nn][r] *= fac[r];

    #pragma unroll
    for (int kt = 0; kt < 2; kt++) {
      short8 ap = *(const short8*)(pbase + fr*128 + ((kt*64 + fq*16) ^ ((fr & 7) << 4)));
      #pragma unroll
      for (int nn = 0; nn < 8; nn++) {
        const int d = nn*16 + fr;
        short8 vf = *(const short8*)((char*)Vs + d*128 + ((kt*64 + fq*16) ^ ((d & 7) << 4)));
        o[nn] = MFMA16(ap, vf, o[nn]);
      }
    }
    __syncthreads();   // all LDS reads of this tile done before next writeKV
  }

  // ---- epilogue: O / l ----
  float inv[4];
  #pragma unroll
  for (int r = 0; r < 4; r++) inv[r] = 1.0f / l_run[r];
  bf16* ao = Aout + (size_t)(b*SS + i0 + w*16)*HH + h*HD;
  #pragma unroll
  for (int nn = 0; nn < 8; nn++)
    #pragma unroll
    for (int r = 0; r < 4; r++)
      stf(ao + (size_t)(fq*4 + r)*HH + nn*16 + fr, o[nn][r] * inv[r]);
}

extern "C" void kernel_launch(void* const* d_in, const int* in_sizes, int n_in,
                              void* d_out, int out_size, void* d_ws, size_t ws_size,
                              hipStream_t stream)
{
  // Workspace (80 MB + 256 B, prior-proven footprint):
  // flag @0 | Q @256 (32MB) | K (8MB) | VT (8MB) | S (32MB).
  // S time-shares: WTq -> {WTk, WTv} -> attention output A. WTo reuses Q region.
  // fp32 mode: Xb (bf16 X, 32MB) lives in d_out (64MB fp32, dead until O-proj).
  char* ws = (char*)d_ws;
  const size_t MB = (size_t)1 << 20;
  int*  flag = (int*)ws;
  bf16* Q  = (bf16*)(ws + 256);
  bf16* K  = (bf16*)(ws + 256 + 32*MB);
  bf16* VT = (bf16*)(ws + 256 + 40*MB);
  bf16* S  = (bf16*)(ws + 256 + 48*MB);
  bf16* WTk = S;                        // 8 MB
  bf16* WTv = S + (size_t)KVD*HH;       // 8 MB
  bf16* WTo = Q;
  bf16* Xb = (bf16*)d_out;              // fp32-mode scratch only (unread in bf16 mode)
  const bf16* X0 = (const bf16*)d_in[0];

  detect_kernel<<<1, 256, 0, stream>>>(d_in[1], flag);
  cvt_x<<<MROWS*HH/8/256, 256, 0, stream>>>(flag, (const float*)d_in[0], Xb);

  // ---- Q projection: 256^2 (single dispatch, flag-branched) ----
  transpose_cvt<<<dim3(HH/32, HH/32, 1), 256, 0, stream>>>(flag, d_in[1], d_in[1], S, S, HH, HH);
  gemm256<0><<<dim3(HH/256, MROWS/256), 512, 0, stream>>>(flag, X0, Xb, S, Q, MROWS, HH, HH);

  // ---- K+V projections fused ----
  transpose_cvt<<<dim3(KVD/32, HH/32, 2), 256, 0, stream>>>(flag, d_in[2], d_in[3], WTk, WTv, HH, KVD);
  gemm_kv<<<dim3(KVD/128, MROWS/128, 2), 256, 0, stream>>>(flag, X0, Xb, WTk, WTv, K, VT, MROWS, KVD, HH);

  // ---- dtype-independent middle ----
  rope_kernel<<<(MROWS*(NH+NKV)*64 + 255)/256, 256, 0, stream>>>(Q, K);
  attn_mfma<<<dim3(SS/64, NH, BB), 256, 0, stream>>>(Q, K, VT, S);   // A -> S

  // ---- output projection: output dtype follows input dtype ----
  transpose_cvt<<<dim3(HH/32, HH/32, 1), 256, 0, stream>>>(flag, d_in[4], d_in[4], WTo, WTo, HH, HH);
  gemm256<1><<<dim3(HH/256, MROWS/256), 512, 0, stream>>>(flag, S, S, WTo, d_out, MROWS, HH, HH);
}

// Round 11
// 691.831 us; speedup vs baseline: 1.0644x; 1.0644x over previous
//
#include <hip/hip_runtime.h>
#include <hip/hip_bf16.h>
#include <math.h>

#define BB 2
#define SS 2048
#define HH 4096
#define NH 32
#define NKV 8
#define HD 128
#define KVD (NKV*HD)    // 1024
#define WIN 512         // mask: j <= i && i-j <= 512
#define MROWS (BB*SS)   // 4096

#define DT_BF16 1
#define DT_F32  2

typedef __hip_bfloat16 bf16;
typedef __attribute__((ext_vector_type(8))) short short8;
typedef __attribute__((ext_vector_type(4))) float f32x4;
typedef __attribute__((ext_vector_type(4))) unsigned short ushort4v;

__device__ __forceinline__ float ldf(const bf16* p){ return __bfloat162float(*p); }
__device__ __forceinline__ float ldf(const float* p){ return *p; }
__device__ __forceinline__ void stf(bf16* p, float v){ *p = __float2bfloat16(v); }
__device__ __forceinline__ void stf(float* p, float v){ *p = v; }

// ---------- dtype detector (prior-session-proven) ----------
__global__ void detect_kernel(const void* __restrict__ w, int* __restrict__ flag)
{
  __shared__ int big;
  if (threadIdx.x == 0) big = 0;
  __syncthreads();
  const unsigned short* u = (const unsigned short*)w;
  for (int i = threadIdx.x; i < 2048; i += 256) {
    int ex = (u[i] >> 7) & 0xFF;
    if (ex >= 160) big = 1;
  }
  __syncthreads();
  if (threadIdx.x == 0) *flag = big ? DT_F32 : DT_BF16;
}

// ---------- X fp32 -> bf16 (gated: fp32 mode only; Y = d_out scratch) ----------
__global__ __launch_bounds__(256)
void cvt_x(const int* __restrict__ flag, const float* __restrict__ X,
           bf16* __restrict__ Y)
{
  if (*flag != DT_F32) return;
  const size_t idx = (size_t)blockIdx.x*256 + threadIdx.x;   // 8 floats/thread
  const f32x4 a = *(const f32x4*)(X + idx*8);
  const f32x4 b = *(const f32x4*)(X + idx*8 + 4);
  union { short8 s; bf16 h[8]; } u;
  #pragma unroll
  for (int j = 0; j < 4; j++) {
    u.h[j]     = __float2bfloat16(a[j]);
    u.h[j + 4] = __float2bfloat16(b[j]);
  }
  *(short8*)(Y + idx*8) = u.s;
}

// ------------- W [Kd,Nd] -> WT [Nd,Kd] bf16, dtype-gated -------------
// Z=2 grid: blockIdx.z selects (W0->D0) or (W1->D1) for fused Wk/Wv transpose.
template<typename TS>
__global__ __launch_bounds__(256)
void transpose_cvt(const int* __restrict__ flag, int mydt,
                   const TS* __restrict__ W0, const TS* __restrict__ W1,
                   bf16* __restrict__ D0, bf16* __restrict__ D1, int Kd, int Nd)
{
  if (*flag != mydt) return;
  const TS* W  = blockIdx.z ? W1 : W0;
  bf16*    WT  = blockIdx.z ? D1 : D0;
  __shared__ float tile[32][33];
  const int n0 = blockIdx.x*32, k0 = blockIdx.y*32;
  const int tx = threadIdx.x & 31, ty = threadIdx.x >> 5;   // ty 0..7
  #pragma unroll
  for (int j = 0; j < 4; j++)
    tile[ty + j*8][tx] = ldf(W + (size_t)(k0 + ty + j*8)*Nd + n0 + tx);
  __syncthreads();
  #pragma unroll
  for (int j = 0; j < 4; j++)
    WT[(size_t)(n0 + ty + j*8)*Kd + k0 + tx] = __float2bfloat16(tile[tx][ty + j*8]);
}

// ======================= 256x256 8-phase MFMA GEMM (round-8 best) =======================
#define MFMA16(a,b,c) __builtin_amdgcn_mfma_f32_16x16x32_bf16(a,b,c,0,0,0)

template<typename TC>
__global__ __launch_bounds__(512)
void gemm256(const int* __restrict__ flag, int mydt,
             const bf16* __restrict__ A, const bf16* __restrict__ Bm,
             TC* __restrict__ C, int M, int N, int K)
{
  if (*flag != mydt) return;
  __shared__ __align__(16) bf16 lds[65536];   // 128 KiB; 16B chunks: A 0..4095, B 4096..8191
  const int tid = threadIdx.x;
  const int w = tid >> 6, lane = tid & 63;
  const int wm = w >> 2, wn = w & 3;
  const int fr = lane & 15, fq = lane >> 4;

  // XCD-aware bijective swizzle (nwg = 256, divisible by 8)
  const int gx = gridDim.x;
  int wg = blockIdx.y*gx + blockIdx.x;
  const int cpx = (gx*gridDim.y) >> 3;
  wg = (wg & 7)*cpx + (wg >> 3);
  const int tM = (wg / gx)*256, tN = (wg % gx)*256;

  const int NT = K >> 6;   // K-tiles of 64

  auto stage = [&](int tt, int s){
    const int dbuf = tt & 1;
    const int hf = s & 1;
    const bf16* src = (s < 2) ? A : Bm;
    const int brow = ((s < 2) ? tM : tN) + hf*128;
    const int cbase = ((s < 2) ? 0 : 4096) + (dbuf*2 + hf)*1024;
    #pragma unroll
    for (int g = 0; g < 2; g++) {
      const int Ch = g*512 + tid;          // chunk 0..1023 within half-tile
      const int r = Ch >> 3, c = Ch & 7;
      const int cs = c ^ (r & 7);
      const bf16* gp = src + (size_t)(brow + r)*K + tt*64 + cs*8;
      char* lp = (char*)lds + (size_t)(cbase + g*512 + w*64)*16;   // + lane*16 by HW
      __builtin_amdgcn_global_load_lds((const __attribute__((address_space(1))) void*)gp,
                                       (__attribute__((address_space(3))) void*)lp, 16, 0, 0);
    }
  };
  auto rdA = [&](int dbuf, int m, int kk) -> short8 {
    const int r = m*16 + fr;                       // row within half (half = wm)
    const int chunk = (dbuf*2 + wm)*1024 + r*8 + ((kk*4 + fq) ^ (r & 7));
    return *(const short8*)((char*)lds + (size_t)chunk*16);
  };
  auto rdB = [&](int dbuf, int n, int kk) -> short8 {
    const int rg = wn*64 + n*16 + fr;              // 0..255
    const int hf = rg >> 7, rr = rg & 127;
    const int chunk = 4096 + (dbuf*2 + hf)*1024 + rr*8 + ((kk*4 + fq) ^ (rr & 7));
    return *(const short8*)((char*)lds + (size_t)chunk*16);
  };

  f32x4 acc[8][4] = {};

  #pragma unroll
  for (int s = 0; s < 4; s++) stage(0, s);
  stage(1, 0); stage(1, 1);
  asm volatile("s_waitcnt vmcnt(4)" ::: "memory");
  __builtin_amdgcn_s_barrier();

  short8 a0[4][2], a1[4][2], b0[2][2], b1[2][2];
  for (int kt = 0; kt < NT; kt++) {
    const int db = kt & 1;
    // -- phase 0: read a0+b0; stage (kt+1).B.h0; MFMA m0-3 x n0-1
    #pragma unroll
    for (int m = 0; m < 4; m++){ a0[m][0]=rdA(db,m,0); a0[m][1]=rdA(db,m,1); }
    #pragma unroll
    for (int n = 0; n < 2; n++){ b0[n][0]=rdB(db,n,0); b0[n][1]=rdB(db,n,1); }
    if (kt+1 < NT) stage(kt+1, 2);
    asm volatile("s_waitcnt lgkmcnt(0)" ::: "memory");
    __builtin_amdgcn_sched_barrier(0);
    __builtin_amdgcn_s_setprio(1);
    #pragma unroll
    for (int m = 0; m < 4; m++)
      #pragma unroll
      for (int n = 0; n < 2; n++){
        acc[m][n] = MFMA16(a0[m][0], b0[n][0], acc[m][n]);
        acc[m][n] = MFMA16(a0[m][1], b0[n][1], acc[m][n]);
      }
    __builtin_amdgcn_s_setprio(0);
    __builtin_amdgcn_s_barrier();
    // -- phase 1: read a1+b1; stage (kt+1).B.h1; MFMA m4-7 x n2-3
    #pragma unroll
    for (int m = 0; m < 4; m++){ a1[m][0]=rdA(db,m+4,0); a1[m][1]=rdA(db,m+4,1); }
    #pragma unroll
    for (int n = 0; n < 2; n++){ b1[n][0]=rdB(db,n+2,0); b1[n][1]=rdB(db,n+2,1); }
    if (kt+1 < NT) stage(kt+1, 3);
    asm volatile("s_waitcnt lgkmcnt(0)" ::: "memory");
    __builtin_amdgcn_sched_barrier(0);
    __builtin_amdgcn_s_setprio(1);
    #pragma unroll
    for (int m = 0; m < 4; m++)
      #pragma unroll
      for (int n = 0; n < 2; n++){
        acc[m+4][n+2] = MFMA16(a1[m][0], b1[n][0], acc[m+4][n+2]);
        acc[m+4][n+2] = MFMA16(a1[m][1], b1[n][1], acc[m+4][n+2]);
      }
    __builtin_amdgcn_s_setprio(0);
    __builtin_amdgcn_s_barrier();       // all dbuf(kt) LDS reads complete
    // -- phase 2: stage (kt+2).A.h0 (dbuf now dead); MFMA m0-3 x n2-3
    if (kt+2 < NT) stage(kt+2, 0);
    __builtin_amdgcn_s_setprio(1);
    #pragma unroll
    for (int m = 0; m < 4; m++)
      #pragma unroll
      for (int n = 0; n < 2; n++){
        acc[m][n+2] = MFMA16(a0[m][0], b1[n][0], acc[m][n+2]);
        acc[m][n+2] = MFMA16(a0[m][1], b1[n][1], acc[m][n+2]);
      }
    __builtin_amdgcn_s_setprio(0);
    __builtin_amdgcn_s_barrier();
    // -- phase 3: stage (kt+2).A.h1; MFMA m4-7 x n0-1
    if (kt+2 < NT) stage(kt+2, 1);
    __builtin_amdgcn_s_setprio(1);
    #pragma unroll
    for (int m = 0; m < 4; m++)
      #pragma unroll
      for (int n = 0; n < 2; n++){
        acc[m+4][n] = MFMA16(a1[m][0], b0[n][0], acc[m+4][n]);
        acc[m+4][n] = MFMA16(a1[m][1], b0[n][1], acc[m+4][n]);
      }
    __builtin_amdgcn_s_setprio(0);
    // -- K-tile boundary: counted wait (never 0 in steady state) + barrier
    if (kt+2 < NT) { asm volatile("s_waitcnt vmcnt(4)" ::: "memory"); }
    else           { asm volatile("s_waitcnt vmcnt(0)" ::: "memory"); }
    __builtin_amdgcn_s_barrier();
  }

  // ---- epilogue: C/D layout col=lane&15, row=(lane>>4)*4+reg ----
  #pragma unroll
  for (int m = 0; m < 8; m++)
    #pragma unroll
    for (int n = 0; n < 4; n++)
      #pragma unroll
      for (int r = 0; r < 4; r++)
        stf(C + (size_t)(tM + wm*128 + m*16 + fq*4 + r)*N + (tN + wn*64 + n*16 + fr),
            acc[m][n][r]);
}

// ---------------- Fused K+V projection (m97 128x128 structure) ----------------
// blockIdx.z: 0 -> K = X@WTk^T (row-major); 1 -> V -> VT[b][kh][d][s].
__global__ __launch_bounds__(256)
void gemm_kv(const int* __restrict__ flag, int mydt, const bf16* __restrict__ A,
             const bf16* __restrict__ WTk, const bf16* __restrict__ WTv,
             bf16* __restrict__ Kout, bf16* __restrict__ VTout, int M, int N, int K)
{
  if (*flag != mydt) return;
  const bool vpath = blockIdx.z != 0;
  const bf16* Bm = vpath ? WTv : WTk;
  __shared__ __align__(16) bf16 As[128*32];
  __shared__ __align__(16) bf16 Bs[128*32];
  const int tid  = threadIdx.x;
  const int w    = tid >> 6;
  const int lane = tid & 63;
  const int wr = w >> 1, wc = w & 1;
  const int tM = blockIdx.y*128, tN = blockIdx.x*128;
  const int srow = tid >> 2;          // 0..63
  const int scol = (tid & 3) * 8;     // 0,8,16,24
  const int fr = lane & 15;
  const int kq = (lane >> 4) * 8;

  f32x4 acc[4][4] = {};

  for (int k0 = 0; k0 < K; k0 += 32) {
    __syncthreads();
    #pragma unroll
    for (int q = 0; q < 2; q++) {
      const int row = q*64 + srow;
      const bf16* ga = A  + (size_t)(tM + row)*K + k0 + scol;
      const bf16* gb = Bm + (size_t)(tN + row)*K + k0 + scol;
      char* la = (char*)As + q*4096 + w*1024;   // wave-uniform base; HW adds lane*16
      char* lb = (char*)Bs + q*4096 + w*1024;
      __builtin_amdgcn_global_load_lds((const __attribute__((address_space(1))) void*)ga,
                                       (__attribute__((address_space(3))) void*)la, 16, 0, 0);
      __builtin_amdgcn_global_load_lds((const __attribute__((address_space(1))) void*)gb,
                                       (__attribute__((address_space(3))) void*)lb, 16, 0, 0);
    }
    __syncthreads();

    short8 af[4], bfr[4];
    #pragma unroll
    for (int m = 0; m < 4; m++) af[m]  = *(const short8*)&As[(wr*64 + m*16 + fr)*32 + kq];
    #pragma unroll
    for (int n = 0; n < 4; n++) bfr[n] = *(const short8*)&Bs[(wc*64 + n*16 + fr)*32 + kq];
    #pragma unroll
    for (int m = 0; m < 4; m++)
      #pragma unroll
      for (int n = 0; n < 4; n++)
        acc[m][n] = MFMA16(af[m], bfr[n], acc[m][n]);
  }

  const int fq = lane >> 4;
  #pragma unroll
  for (int m = 0; m < 4; m++)
    #pragma unroll
    for (int n = 0; n < 4; n++)
      #pragma unroll
      for (int r = 0; r < 4; r++) {
        const int gm = tM + wr*64 + m*16 + fq*4 + r;
        const int gn = tN + wc*64 + n*16 + fr;
        if (vpath) {
          // VT[b][kh][d][s]: b=gm>>11, s=gm&2047, kh=gn>>7, d=gn&127
          size_t idx = ((size_t)((gm >> 11)*NKV + (gn >> 7)))*((size_t)HD*SS)
                     + (size_t)(gn & 127)*SS + (gm & 2047);
          stf(VTout + idx, acc[m][n][r]);
        } else {
          stf(Kout + (size_t)gm*N + gn, acc[m][n][r]);
        }
      }
}

// ---------------- RoPE (in place, bf16 [MROWS, nh*HD]) ----------------
__global__ void rope_kernel(bf16* __restrict__ X, int nh)
{
  int idx = blockIdx.x*blockDim.x + threadIdx.x;
  int total = MROWS * nh * 64;
  if (idx >= total) return;
  int f   = idx & 63;
  int h   = (idx >> 6) % nh;
  int row = (idx >> 6) / nh;
  int s   = row & (SS - 1);
  float ang = (float)s * exp2f((float)f * -0.20762050593046014f);
  float sv, cv;
  __sincosf(ang, &sv, &cv);
  size_t base = (size_t)row*nh*HD + (size_t)h*HD;
  float x1 = ldf(X + base + f), x2 = ldf(X + base + 64 + f);
  stf(X + base + f,      x1*cv - x2*sv);
  stf(X + base + 64 + f, x2*cv + x1*sv);
}

// ---------------- Flash-tile MFMA attention (swapped-QK^T softmax, T12) ----------------
// Block = (b, h, 64-row q-tile); 4 waves x 16 q-rows; KV tiles of 64.
// QK^T computed as mfma(K,Q): lane holds S[j = jf*16+fq*4+r][q = fr] ->
// per-lane scalar m/l (2 shfl_xor instead of 8), P packed as 4x 8B stores
// (4 consecutive j per lane). fac/l broadcast back via __shfl(., fq*4+r).
__global__ __launch_bounds__(256, 2)
void attn_mfma(const bf16* __restrict__ Q, const bf16* __restrict__ K,
               const bf16* __restrict__ VT, bf16* __restrict__ Aout)
{
  int flat = (blockIdx.z*NH + blockIdx.y)*(SS/64) + blockIdx.x;
  flat = (flat & 7)*(BB*NH*(SS/64)/8) + (flat >> 3);   // bijective (2048 % 8 == 0)
  const int i0 = (flat & 31) * 64;
  const int h  = (flat >> 5) & 31;
  const int b  = flat >> 10;
  const int kh = h >> 2;
  const int tid = threadIdx.x;
  const int w = tid >> 6, lane = tid & 63;
  const int fr = lane & 15, fq = lane >> 4;

  __shared__ __align__(16) bf16 Ks[64*128];
  __shared__ __align__(16) bf16 Vs[128*64];
  __shared__ __align__(16) bf16 Ps[4][16*64];

  // ---- Q fragments direct from global (once per block); B-operand ----
  const int qrow = w*16 + fr;
  const bf16* gq = Q + (size_t)(b*SS + i0 + qrow)*HH + h*HD + fq*8;
  short8 qf[4];
  #pragma unroll
  for (int kk = 0; kk < 4; kk++) qf[kk] = *(const short8*)(gq + kk*32);

  // T14 staging registers (4 K + 4 V short8 per thread)
  short8 kreg[4], vreg[4];
  auto loadKV = [&](int j0){
    const bf16* gk = K + (size_t)(b*SS + j0)*KVD + kh*HD;
    #pragma unroll
    for (int it = 0; it < 4; it++) {
      int slot = tid + it*256;
      int r = slot >> 4, cg = slot & 15;
      kreg[it] = *(const short8*)(gk + (size_t)r*KVD + cg*8);
    }
    const bf16* gv = VT + ((size_t)(b*NKV + kh)*HD)*SS + j0;
    #pragma unroll
    for (int it = 0; it < 4; it++) {
      int slot = tid + it*256;
      int d = slot >> 3, jg = slot & 7;
      vreg[it] = *(const short8*)(gv + (size_t)d*SS + jg*8);
    }
  };
  auto writeKV = [&](){
    #pragma unroll
    for (int it = 0; it < 4; it++) {
      int slot = tid + it*256;
      int r = slot >> 4, cg = slot & 15;
      *(short8*)((char*)Ks + r*256 + ((cg*16) ^ ((r & 7) << 4))) = kreg[it];
      int d = slot >> 3, jg = slot & 7;
      *(short8*)((char*)Vs + d*128 + ((jg*16) ^ ((d & 7) << 4))) = vreg[it];
    }
  };

  const float scale = 0.08838834764831845f;   // 1/sqrt(128)
  f32x4 o[8];
  #pragma unroll
  for (int nn = 0; nn < 8; nn++) o[nn] = (f32x4){0.f, 0.f, 0.f, 0.f};
  float m_run = -1e30f;   // per-lane: q-row = i0 + w*16 + fr
  float l_run = 0.f;

  const int j0_lo = (i0 >= WIN) ? (i0 - WIN) : 0;
  loadKV(j0_lo);

  const int iq = i0 + w*16 + fr;   // this lane's q-row (fixed)

  for (int j0 = j0_lo; j0 <= i0; j0 += 64) {
    // ---- write staged regs -> LDS (prev tile's LDS reads done: end barrier) ----
    writeKV();
    __syncthreads();

    // ---- QK^T swapped: sv[jf][r] = S[j = j0+jf*16+fq*4+r][q = iq] ----
    f32x4 sv[4];
    #pragma unroll
    for (int jf = 0; jf < 4; jf++) sv[jf] = (f32x4){0.f, 0.f, 0.f, 0.f};
    #pragma unroll
    for (int kk = 0; kk < 4; kk++) {
      #pragma unroll
      for (int jf = 0; jf < 4; jf++) {
        const int krow = jf*16 + fr;
        short8 kf = *(const short8*)((char*)Ks + krow*256 + ((kk*64 + fq*16) ^ ((krow & 7) << 4)));
        sv[jf] = MFMA16(kf, qf[kk], sv[jf]);   // SWAPPED: K as A, Q as B
      }
    }

    // ---- T14: issue next tile's loads now; latency hides under softmax+PV ----
    if (j0 + 64 <= i0) loadKV(j0 + 64);

    // ---- scale + mask (j is now the lane-spread dim) ----
    const bool needmask = !((j0 >= i0 - 448) && (j0 <= i0 - 64));
    #pragma unroll
    for (int jf = 0; jf < 4; jf++)
      #pragma unroll
      for (int r = 0; r < 4; r++) {
        float x = sv[jf][r] * scale;
        if (needmask) {
          int jv = j0 + jf*16 + fq*4 + r;
          if (jv > iq || iq - jv > WIN) x = -1e30f;
        }
        sv[jf][r] = x;
      }

    // ---- online softmax: per-lane scalar state, 2-shfl reduce ----
    float t = -1e30f;
    #pragma unroll
    for (int jf = 0; jf < 4; jf++)
      #pragma unroll
      for (int r = 0; r < 4; r++) t = fmaxf(t, sv[jf][r]);
    t = fmaxf(t, __shfl_xor(t, 16));
    t = fmaxf(t, __shfl_xor(t, 32));
    const float mn = fmaxf(m_run, t);
    const float fac = __expf(m_run - mn);
    m_run = mn;
    float sum = 0.f;
    #pragma unroll
    for (int jf = 0; jf < 4; jf++)
      #pragma unroll
      for (int r = 0; r < 4; r++) {
        float p = __expf(sv[jf][r] - mn);
        sv[jf][r] = p;
        sum += p;
      }
    sum += __shfl_xor(sum, 16);
    sum += __shfl_xor(sum, 32);
    l_run = l_run*fac + sum;

    // ---- P -> per-wave LDS: 4 packed 8B stores (4 consecutive j per lane) ----
    char* pbase = (char*)(&Ps[w][0]);
    #pragma unroll
    for (int jf = 0; jf < 4; jf++) {
      ushort4v pk;
      #pragma unroll
      for (int r = 0; r < 4; r++) {
        union { bf16 bx; unsigned short sx; } cv;
        cv.bx = __float2bfloat16(sv[jf][r]);
        pk[r] = cv.sx;
      }
      *(ushort4v*)(pbase + fr*128 + ((jf*32 + fq*8) ^ ((fr & 7) << 4))) = pk;
    }

    // ---- rescale O: fac for q-row fq*4+r lives in lane fq*4+r ----
    float fr4[4];
    #pragma unroll
    for (int r = 0; r < 4; r++) fr4[r] = __shfl(fac, fq*4 + r);
    #pragma unroll
    for (int nn = 0; nn < 8; nn++)
      #pragma unroll
      for (int r = 0; r < 4; r++) o[nn][r] *= fr4[r];

    // ---- PV from Ps/Vs (unchanged) ----
    #pragma unroll
    for (int kt = 0; kt < 2; kt++) {
      short8 ap = *(const short8*)(pbase + fr*128 + ((kt*64 + fq*16) ^ ((fr & 7) << 4)));
      #pragma unroll
      for (int nn = 0; nn < 8; nn++) {
        const int d = nn*16 + fr;
        short8 vf = *(const short8*)((char*)Vs + d*128 + ((kt*64 + fq*16) ^ ((d & 7) << 4)));
        o[nn] = MFMA16(ap, vf, o[nn]);
      }
    }
    __syncthreads();   // all LDS reads of this tile done before next writeKV
  }

  // ---- epilogue: O / l (l for q-row fq*4+r from lane fq*4+r) ----
  const float linv = 1.0f / l_run;
  float inv[4];
  #pragma unroll
  for (int r = 0; r < 4; r++) inv[r] = __shfl(linv, fq*4 + r);
  bf16* ao = Aout + (size_t)(b*SS + i0 + w*16)*HH + h*HD;
  #pragma unroll
  for (int nn = 0; nn < 8; nn++)
    #pragma unroll
    for (int r = 0; r < 4; r++)
      stf(ao + (size_t)(fq*4 + r)*HH + nn*16 + fr, o[nn][r] * inv[r]);
}

extern "C" void kernel_launch(void* const* d_in, const int* in_sizes, int n_in,
                              void* d_out, int out_size, void* d_ws, size_t ws_size,
                              hipStream_t stream)
{
  // Workspace (80 MB + 256 B, prior-proven footprint):
  // flag @0 | Q @256 (32MB) | K (8MB) | VT (8MB) | S (32MB).
  // S time-shares: WTq -> {WTk, WTv} -> attention output A. WTo reuses Q region.
  // fp32 mode: Xb (bf16 X, 32MB) lives in d_out (64MB fp32, dead until O-proj).
  char* ws = (char*)d_ws;
  const size_t MB = (size_t)1 << 20;
  int*  flag = (int*)ws;
  bf16* Q  = (bf16*)(ws + 256);
  bf16* K  = (bf16*)(ws + 256 + 32*MB);
  bf16* VT = (bf16*)(ws + 256 + 40*MB);
  bf16* S  = (bf16*)(ws + 256 + 48*MB);
  bf16* WTk = S;                        // 8 MB
  bf16* WTv = S + (size_t)KVD*HH;       // 8 MB
  bf16* WTo = Q;
  bf16* Xb = (bf16*)d_out;              // fp32-mode scratch only (gated)
  const bf16* X0 = (const bf16*)d_in[0];

  detect_kernel<<<1, 256, 0, stream>>>(d_in[1], flag);
  cvt_x<<<MROWS*HH/8/256, 256, 0, stream>>>(flag, (const float*)d_in[0], Xb);

  auto tr1 = [&](const void* W, int Kd, int Nd, bf16* dst){
    dim3 g(Nd/32, Kd/32, 1);
    transpose_cvt<bf16 ><<<g,256,0,stream>>>(flag, DT_BF16, (const bf16 *)W, (const bf16 *)W, dst, dst, Kd, Nd);
    transpose_cvt<float><<<g,256,0,stream>>>(flag, DT_F32 , (const float*)W, (const float*)W, dst, dst, Kd, Nd);
  };

  // ---- Q projection: 256^2 8-phase ----
  tr1(d_in[1], HH, HH, S);
  {
    dim3 g(HH/256, MROWS/256);
    gemm256<bf16><<<g,512,0,stream>>>(flag, DT_BF16, X0, S, Q, MROWS, HH, HH);
    gemm256<bf16><<<g,512,0,stream>>>(flag, DT_F32 , Xb, S, Q, MROWS, HH, HH);
  }
  // ---- K+V projections fused ----
  {
    dim3 gt(KVD/32, HH/32, 2);
    transpose_cvt<bf16 ><<<gt,256,0,stream>>>(flag, DT_BF16, (const bf16 *)d_in[2], (const bf16 *)d_in[3], WTk, WTv, HH, KVD);
    transpose_cvt<float><<<gt,256,0,stream>>>(flag, DT_F32 , (const float*)d_in[2], (const float*)d_in[3], WTk, WTv, HH, KVD);
    dim3 g(KVD/128, MROWS/128, 2);
    gemm_kv<<<g,256,0,stream>>>(flag, DT_BF16, X0, WTk, WTv, K, VT, MROWS, KVD, HH);
    gemm_kv<<<g,256,0,stream>>>(flag, DT_F32 , Xb, WTk, WTv, K, VT, MROWS, KVD, HH);
  }

  // ---- dtype-independent middle ----
  rope_kernel<<<(MROWS*NH *64 + 255)/256, 256, 0, stream>>>(Q, NH);
  rope_kernel<<<(MROWS*NKV*64 + 255)/256, 256, 0, stream>>>(K, NKV);
  attn_mfma<<<dim3(SS/64, NH, BB), 256, 0, stream>>>(Q, K, VT, S);   // A -> S

  // ---- output projection: output dtype follows input dtype ----
  tr1(d_in[4], HH, HH, WTo);
  {
    dim3 g(HH/256, MROWS/256);
    gemm256<bf16 ><<<g,512,0,stream>>>(flag, DT_BF16, S, WTo, (bf16 *)d_out, MROWS, HH, HH);
    gemm256<float><<<g,512,0,stream>>>(flag, DT_F32 , S, WTo, (float*)d_out, MROWS, HH, HH);
  }
}